// Round 2
// baseline (105.107 us; speedup 1.0000x reference)
//
#include <hip/hip_runtime.h>
#include <math.h>

#define BATCH 16
#define NTGT  50
#define NTOT  (BATCH * NTGT)   // 800 targets
#define N_CLASSES 80
#define N_BINS 16
#define NBLK  200              // 4 targets (waves) per 256-thread block

// Fused kernel: 200 blocks x 256 threads. Each 64-lane wave handles one
// target (gather + focal + DFL). Lane l loads channel l (dist bins),
// channel 64+l (classes 0..63), channel 128+l for l<16 (classes 64..79).
// The last block to finish (atomic ticket) performs the final reduction
// with FP order identical to the previous standalone reduce kernel.
__global__ void __launch_bounds__(256) detloss_fused(
    const float* __restrict__ f0, const float* __restrict__ f1,
    const float* __restrict__ f2, const float* __restrict__ tgts,
    float2* __restrict__ partials, unsigned int* __restrict__ counter,
    float* __restrict__ out) {
  __shared__ float sc[256], sb[256];
  __shared__ unsigned int s_ticket;

  const int tid  = threadIdx.x;
  const int wave = tid >> 6;
  const int lane = tid & 63;
  const int t = blockIdx.x * 4 + wave;   // 0..799
  const int b = t / NTGT;

  // targets[t]: 6 floats at byte offset 24*t -> 8B aligned, load as 3x float2
  const float2* tp2 = (const float2*)(tgts + (size_t)t * 6);
  const float2 ta = tp2[0], tb = tp2[1], tc = tp2[2];
  const float cx = ta.y, cy = tb.x, w = tb.y, h = tc.x;
  const int cls_t = (int)ta.x;
  const int layer = (int)tc.y;

  const float* feat; int H, W;
  if (layer == 0)      { feat = f0; H = 80; W = 80; }
  else if (layer == 1) { feat = f1; H = 40; W = 40; }
  else                 { feat = f2; H = 20; W = 20; }

  int fx = (int)(cx * (float)W); fx = min(max(fx, 0), W - 1);
  int fy = (int)(cy * (float)H); fy = min(max(fy, 0), H - 1);

  const int C = 4 * N_BINS + N_CLASSES;   // 144
  const size_t hw = (size_t)H * (size_t)W;
  const float* base = feat + (size_t)b * C * hw + (size_t)fy * W + (size_t)fx;

  // Scattered gathers: channel c lives at base[c*hw]
  const float xd = base[(size_t)lane * hw];                                   // dist ch 0..63
  const float x1 = base[(size_t)(64 + lane) * hw];                            // class lane
  const float x2 = (lane < 16) ? base[(size_t)(128 + lane) * hw] : -INFINITY; // class 64+lane

  // ---- focal classification loss: log_softmax over 80 classes ----
  float m = fmaxf(x1, x2);
  #pragma unroll
  for (int off = 32; off; off >>= 1) m = fmaxf(m, __shfl_xor(m, off));
  float s = expf(x1 - m) + ((lane < 16) ? expf(x2 - m) : 0.0f);
  #pragma unroll
  for (int off = 32; off; off >>= 1) s += __shfl_xor(s, off);
  const float lse = m + logf(s);
  const float v1 = __shfl(x1, cls_t & 63);
  const float v2 = __shfl(x2, cls_t & 15);
  const float logit_t = (cls_t < 64) ? v1 : v2;
  const float ce = lse - logit_t;
  const float pt = expf(-ce);
  const float om = 1.0f - pt;
  const float focal = om * om * ce;        // ALPHA=1, GAMMA=2

  // ---- DFL box loss: 4 sides x 16 bins; 16-lane group per side ----
  float m16 = xd;
  #pragma unroll
  for (int off = 8; off; off >>= 1) m16 = fmaxf(m16, __shfl_xor(m16, off));
  float s16 = expf(xd - m16);
  #pragma unroll
  for (int off = 8; off; off >>= 1) s16 += __shfl_xor(s16, off);
  const float lse16 = m16 + logf(s16);
  const float lp = xd - lse16;             // log-softmax of this lane's bin

  const int side = lane >> 4;              // 0:w 1:h 2:w 3:h
  const float gtv = (side & 1) ? (h * 0.5f * (float)H) : (w * 0.5f * (float)W);
  const float tv = fminf(fmaxf(gtv, 0.0f), (float)(N_BINS - 1) - 1e-6f);
  const int li = (int)tv;                  // floor, tv >= 0
  const float wl = (float)(li + 1) - tv;
  const float wr = tv - (float)li;
  const int gb = lane & 48;                // group base lane
  const float lp_l = __shfl(lp, gb | li);
  const float lp_r = __shfl(lp, gb | min(li + 1, N_BINS - 1));
  float dfl = -(lp_l * wl + lp_r * wr);
  dfl = ((lane & 15) == 0) ? dfl : 0.0f;   // one contribution per side
  float box = dfl;
  #pragma unroll
  for (int off = 32; off; off >>= 1) box += __shfl_xor(box, off);

  if (lane == 0) partials[t] = make_float2(focal, box);

  // ---- last-block-done final reduction (device-scope handoff) ----
  __syncthreads();
  if (tid == 0) {
    __threadfence();                       // release: flush partials to device scope
    s_ticket = atomicAdd(counter, 1u);     // device-scope RMW
  }
  __syncthreads();
  if (s_ticket == NBLK - 1) {              // block-uniform branch
    __threadfence();                       // acquire: invalidate stale cached lines
    float c = 0.0f, bx = 0.0f;
    for (int i = tid; i < NTOT; i += 256) {
      float2 p = partials[i]; c += p.x; bx += p.y;
    }
    sc[tid] = c; sb[tid] = bx;
    __syncthreads();
    #pragma unroll
    for (int off = 128; off; off >>= 1) {
      if (tid < off) { sc[tid] += sc[tid + off]; sb[tid] += sb[tid + off]; }
      __syncthreads();
    }
    if (tid == 0) {
      out[0] = sc[0] + sb[0];   // total (CLS_WEIGHT = BOX_WEIGHT = 1)
      out[1] = sc[0];           // total_cls
      out[2] = sb[0];           // total_box
    }
  }
}

extern "C" void kernel_launch(void* const* d_in, const int* in_sizes, int n_in,
                              void* d_out, int out_size, void* d_ws, size_t ws_size,
                              hipStream_t stream) {
  const float* f0 = (const float*)d_in[0];   // [16,144,80,80]
  const float* f1 = (const float*)d_in[1];   // [16,144,40,40]
  const float* f2 = (const float*)d_in[2];   // [16,144,20,20]
  const float* tg = (const float*)d_in[3];   // [16,50,6]

  float2* partials = (float2*)d_ws;                           // 800*8 = 6400 B
  unsigned int* counter = (unsigned int*)((char*)d_ws + 8192);

  // Zero the ticket counter each replay (d_ws is re-poisoned to 0xAA).
  // hipMemsetAsync is graph-capturable (becomes a memset node).
  hipMemsetAsync(counter, 0, sizeof(unsigned int), stream);

  detloss_fused<<<NBLK, 256, 0, stream>>>(f0, f1, f2, tg, partials, counter,
                                          (float*)d_out);
}

// Round 3
// 101.215 us; speedup vs baseline: 1.0385x; 1.0385x over previous
//
#include <hip/hip_runtime.h>
#include <math.h>

#define BATCH 16
#define NTGT  50
#define N_CLASSES 80
#define N_BINS 16
// C = 4*N_BINS + N_CLASSES = 144

// One wavefront (64 lanes) per target. Lane l loads channel l (dist bins),
// channel 64+l (classes 0..63), and channel 128+l for l<16 (classes 64..79).
__global__ void __launch_bounds__(64) detloss_gather(
    const float* __restrict__ f0, const float* __restrict__ f1,
    const float* __restrict__ f2, const float* __restrict__ tgts,
    float2* __restrict__ partials) {
  const int t = blockIdx.x;            // 0 .. BATCH*NTGT-1
  const int b = t / NTGT;
  const int lane = threadIdx.x;        // 0..63

  const float* tp = tgts + (size_t)t * 6;
  const float t0 = tp[0], cx = tp[1], cy = tp[2], w = tp[3], h = tp[4], t5 = tp[5];
  const int cls_t = (int)t0;
  const int layer = (int)t5;

  const float* feat; int H, W;
  if (layer == 0)      { feat = f0; H = 80; W = 80; }
  else if (layer == 1) { feat = f1; H = 40; W = 40; }
  else                 { feat = f2; H = 20; W = 20; }

  int fx = (int)(cx * (float)W); fx = min(max(fx, 0), W - 1);
  int fy = (int)(cy * (float)H); fy = min(max(fy, 0), H - 1);

  const int C = 4 * N_BINS + N_CLASSES;          // 144
  const size_t hw = (size_t)H * (size_t)W;
  const float* base = feat + (size_t)b * C * hw + (size_t)fy * W + (size_t)fx;

  // Scattered gathers: channel c lives at base[c*hw]
  const float xd = base[(size_t)lane * hw];                               // dist ch 0..63
  const float x1 = base[(size_t)(64 + lane) * hw];                        // class lane (0..63)
  const float x2 = (lane < 16) ? base[(size_t)(128 + lane) * hw] : -INFINITY; // class 64+lane

  // ---- focal classification loss: log_softmax over 80 classes ----
  float m = fmaxf(x1, x2);
  #pragma unroll
  for (int off = 32; off; off >>= 1) m = fmaxf(m, __shfl_xor(m, off));
  float s = expf(x1 - m) + ((lane < 16) ? expf(x2 - m) : 0.0f);
  #pragma unroll
  for (int off = 32; off; off >>= 1) s += __shfl_xor(s, off);
  const float lse = m + logf(s);
  const float v1 = __shfl(x1, cls_t & 63);
  const float v2 = __shfl(x2, cls_t & 15);
  const float logit_t = (cls_t < 64) ? v1 : v2;
  const float ce = lse - logit_t;
  const float pt = expf(-ce);
  const float om = 1.0f - pt;
  const float focal = om * om * ce;              // ALPHA=1, GAMMA=2

  // ---- DFL box loss: 4 sides x 16 bins; 16-lane group per side ----
  float m16 = xd;
  #pragma unroll
  for (int off = 8; off; off >>= 1) m16 = fmaxf(m16, __shfl_xor(m16, off));
  float s16 = expf(xd - m16);
  #pragma unroll
  for (int off = 8; off; off >>= 1) s16 += __shfl_xor(s16, off);
  const float lse16 = m16 + logf(s16);
  const float lp = xd - lse16;                   // log-softmax of this lane's bin

  const int side = lane >> 4;                    // 0:w 1:h 2:w 3:h
  const float gtv = (side & 1) ? (h * 0.5f * (float)H) : (w * 0.5f * (float)W);
  const float tv = fminf(fmaxf(gtv, 0.0f), (float)(N_BINS - 1) - 1e-6f);
  const int li = (int)tv;                        // floor, tv >= 0
  const float wl = (float)(li + 1) - tv;
  const float wr = tv - (float)li;
  const int gb = lane & 48;                      // group base lane
  const float lp_l = __shfl(lp, gb | li);
  const float lp_r = __shfl(lp, gb | min(li + 1, N_BINS - 1));
  float dfl = -(lp_l * wl + lp_r * wr);
  dfl = ((lane & 15) == 0) ? dfl : 0.0f;         // one contribution per side
  float box = dfl;
  #pragma unroll
  for (int off = 32; off; off >>= 1) box += __shfl_xor(box, off);

  if (lane == 0) partials[t] = make_float2(focal, box);
}

// Deterministic single-block tree reduction of the 800 partials.
__global__ void __launch_bounds__(256) detloss_reduce(
    const float2* __restrict__ partials, float* __restrict__ out) {
  __shared__ float sc[256], sb[256];
  const int tid = threadIdx.x;
  float c = 0.0f, bx = 0.0f;
  for (int i = tid; i < BATCH * NTGT; i += 256) {
    float2 p = partials[i]; c += p.x; bx += p.y;
  }
  sc[tid] = c; sb[tid] = bx;
  __syncthreads();
  #pragma unroll
  for (int off = 128; off; off >>= 1) {
    if (tid < off) { sc[tid] += sc[tid + off]; sb[tid] += sb[tid + off]; }
    __syncthreads();
  }
  if (tid == 0) {
    out[0] = sc[0] + sb[0];   // total = CLS_WEIGHT*cls + BOX_WEIGHT*box (weights = 1)
    out[1] = sc[0];           // total_cls
    out[2] = sb[0];           // total_box
  }
}

extern "C" void kernel_launch(void* const* d_in, const int* in_sizes, int n_in,
                              void* d_out, int out_size, void* d_ws, size_t ws_size,
                              hipStream_t stream) {
  const float* f0 = (const float*)d_in[0];   // [16,144,80,80]
  const float* f1 = (const float*)d_in[1];   // [16,144,40,40]
  const float* f2 = (const float*)d_in[2];   // [16,144,20,20]
  const float* tg = (const float*)d_in[3];   // [16,50,6]
  float2* partials = (float2*)d_ws;          // 800 float2 = 6.4 KB

  detloss_gather<<<BATCH * NTGT, 64, 0, stream>>>(f0, f1, f2, tg, partials);
  detloss_reduce<<<1, 256, 0, stream>>>(partials, (float*)d_out);
}